// Round 1
// baseline (258.947 us; speedup 1.0000x reference)
//
#include <hip/hip_runtime.h>

// ---------------------------------------------------------------------------
// LSTM (Alex Graves) single step, batch 8192 — fused GEMM+epilogue, r6.
// r5 (128x128 m97-structure) -> 256x256 tile, 2-phase double-buffered LDS
// (T3-minimum recipe): stage(t+1) overlaps compute(t); ONE barrier per
// K-step (implicit vmcnt(0)+lgkmcnt(0) drain at __syncthreads). 12 K-steps.
//   A = [H | x[:,n,:]]  (8192 x 768)  fp16-packed
//   W rows permuted:  row c = gate g=(c>>4)&3, unit jj=((c>>6)<<4)|(c&15)
//     -> register j = gate, lane&15 = jj: epilogue entirely in registers.
//   out[0:8192*512) = cm ; out[8192*512:) = h
// pack_AW: 8 rows/block (1280 blocks) to amortize launch machinery.
// ---------------------------------------------------------------------------

typedef _Float16 half8 __attribute__((ext_vector_type(8)));
typedef _Float16 half4v __attribute__((ext_vector_type(4)));
typedef float floatx4 __attribute__((ext_vector_type(4)));

#define BATCH 8192
#define NSTEPS 16
#define IN_F 256
#define OUT_F 512
#define KDIM 768    // OUT_F + IN_F
#define NDIM 2048   // 4 * OUT_F
#define HSIZE ((size_t)BATCH * OUT_F)

#define BM 256
#define BN 256
#define BK 64
#define NKT (KDIM / BK)   // 12

__device__ __forceinline__ void async_copy16(const void* gptr, void* lptr) {
  __builtin_amdgcn_global_load_lds(
      (const __attribute__((address_space(1))) unsigned int*)gptr,
      (__attribute__((address_space(3))) unsigned int*)lptr,
      16, 0, 0);
}

__device__ __forceinline__ float sigmoidf_(float x) {
  return 1.0f / (1.0f + __expf(-x));
}

__device__ __forceinline__ float tanhf_(float x) {
  x = fminf(fmaxf(x, -20.0f), 20.0f);   // __expf(|2x|>~176) would inf->NaN
  float e = __expf(2.0f * x);
  return (e - 1.0f) / (e + 1.0f);
}

// ------------------- merged pack: A rows then W rows -----------------------
// 8 rows per block: 1280 blocks x 192 thr (vs 10240 tiny blocks in r5 —
// launch machinery dominated a 47 MB / ~7.5 us traffic-floor kernel).
#define PACK_ROWS 8
__global__ void pack_AW(const float* __restrict__ H, const float* __restrict__ x,
                        const int* __restrict__ nptr,
                        const float* __restrict__ fg_w_h, const float* __restrict__ fg_w_x,
                        const float* __restrict__ ig_w_h, const float* __restrict__ ig_w_x,
                        const float* __restrict__ in_w_h, const float* __restrict__ in_w_x,
                        const float* __restrict__ og_w_h, const float* __restrict__ og_w_x,
                        _Float16* __restrict__ A, _Float16* __restrict__ W) {
  const int k = threadIdx.x * 4;
  const int n = *nptr;
  const int row0 = blockIdx.x * PACK_ROWS;
#pragma unroll
  for (int rr = 0; rr < PACK_ROWS; ++rr) {
    const int blk = row0 + rr;
    const float* src;
    _Float16* dst;
    if (blk < BATCH) {
      const int b = blk;
      if (k < OUT_F) {
        src = H + (size_t)b * OUT_F + k;
      } else {
        src = x + ((size_t)b * NSTEPS + n) * IN_F + (k - OUT_F);
      }
      dst = A + (size_t)b * KDIM + k;
    } else {
      const int row = blk - BATCH;
      const int g  = (row >> 4) & 3;
      const int jj = ((row >> 6) << 4) | (row & 15);
      if (k < OUT_F) {
        const float* wh = (g == 0) ? fg_w_h : (g == 1) ? ig_w_h : (g == 2) ? in_w_h : og_w_h;
        src = wh + (size_t)jj * OUT_F + k;
      } else {
        const float* wx = (g == 0) ? fg_w_x : (g == 1) ? ig_w_x : (g == 2) ? in_w_x : og_w_x;
        src = wx + (size_t)jj * IN_F + (k - OUT_F);
      }
      dst = W + (size_t)row * KDIM + k;
    }
    float4 v = *(const float4*)src;
    half4v h = {(_Float16)v.x, (_Float16)v.y, (_Float16)v.z, (_Float16)v.w};
    *(half4v*)dst = h;
  }
}

// ---------------------- fused GEMM + gate epilogue -------------------------
// 256x256 tile, BK=64, 512 thr / 8 waves (2M x 4N), each wave 128x64.
// LDS: 2 x (As 32KB + Bs 32KB) = 128 KB double-buffer.
// 16B-granule XOR swizzle applied on the GLOBAL address side (LDS dest is
// linear — global_load_lds requirement), same involution on the read side.
// 2-phase K-loop: issue stage(t+1) into the other buffer, ds_read+MFMA from
// current, then ONE __syncthreads (compiler emits vmcnt(0) lgkmcnt(0) drain
// = the counted wait for next tile). 13 barriers total vs r5's 24.
__global__ __launch_bounds__(512, 2) void gemm_lstm(
    const _Float16* __restrict__ A, const _Float16* __restrict__ W,
    const float* __restrict__ C,
    const float* __restrict__ fg_w_c, const float* __restrict__ fg_b,
    const float* __restrict__ ig_w_c, const float* __restrict__ ig_b,
    const float* __restrict__ in_b,
    const float* __restrict__ og_w_cn, const float* __restrict__ og_b,
    float* __restrict__ out) {
  __shared__ __align__(16) char smem[131072];
  // buffer p: As at p*65536, Bs at p*65536 + 32768   (p = 0,1)
  // epilogue: cmS = smem[0,64K) 256x64 f32, hS = smem[64K,128K)

  const int tid = threadIdx.x;
  const int lane = tid & 63;
  const int wave = tid >> 6;       // 0..7
  const int quad = lane >> 4;
  const int l16 = lane & 15;
  const int wm = wave >> 2;        // 0..1  (M half: 128 rows)
  const int wn = wave & 3;         // 0..3  (N quarter: 64 cols)
  const int m0 = blockIdx.y * BM;
  const int n0 = blockIdx.x * BN;

  // this lane's output unit (wave's 64 N-cols = 16 units x 4 gates)
  const int jj = (((n0 + wn * 64) >> 6) << 4) | l16;
  const float fwc = fg_w_c[jj], fb = fg_b[jj];
  const float iwc = ig_w_c[jj], ib = ig_b[jj];
  const float nb  = in_b[jj];
  const float owc = og_w_cn[jj], ob = og_b[jj];

  floatx4 acc[8][4] = {};

  auto stage = [&](int p, int kt) {
    _Float16* As = (_Float16*)(smem + p * 65536);
    _Float16* Bs = (_Float16*)(smem + p * 65536 + 32768);
#pragma unroll
    for (int r = 0; r < 4; ++r) {
      const int g = r * 512 + tid;       // 16B granule index, lane-linear
      const int row = g >> 3;            // 0..255
      const int cl = g & 7;
      const int cg = cl ^ (row & 7);     // swizzled global chunk
      async_copy16(A + (size_t)(m0 + row) * KDIM + kt + cg * 8, As + g * 8);
      async_copy16(W + (size_t)(n0 + row) * KDIM + kt + cg * 8, Bs + g * 8);
    }
  };

  stage(0, 0);
  __syncthreads();   // vmcnt(0) drain: buffer 0 ready

  int cur = 0;
  for (int t = 0; t < NKT; ++t) {
    if (t + 1 < NKT) stage(cur ^ 1, (t + 1) * BK);   // overlaps compute below
    const _Float16* As = (const _Float16*)(smem + cur * 65536);
    const _Float16* Bs = (const _Float16*)(smem + cur * 65536 + 32768);
#pragma unroll
    for (int ks = 0; ks < 2; ++ks) {
      half8 af[8], bf[4];
#pragma unroll
      for (int j = 0; j < 4; ++j) {
        const int row = wn * 64 + j * 16 + l16;
        const int chunk = ks * 4 + quad;
        const int gran = row * 8 + (chunk ^ (row & 7));
        bf[j] = *(const half8*)(Bs + gran * 8);
      }
#pragma unroll
      for (int i = 0; i < 8; ++i) {
        const int row = wm * 128 + i * 16 + l16;
        const int chunk = ks * 4 + quad;
        const int gran = row * 8 + (chunk ^ (row & 7));
        af[i] = *(const half8*)(As + gran * 8);
      }
#pragma unroll
      for (int i = 0; i < 8; ++i)
#pragma unroll
        for (int j = 0; j < 4; ++j)
          acc[i][j] = __builtin_amdgcn_mfma_f32_16x16x32_f16(af[i], bf[j], acc[i][j], 0, 0, 0);
    }
    __syncthreads();   // drains this step's ds_reads AND next tile's loads
    cur ^= 1;
  }

  // ---- epilogue. C/D: col=lane&15 (=jj lane), row=quad*4+r ----
  // last loop barrier already fenced all LDS reads; safe to reuse smem.
  float* cmS = (float*)smem;              // 256 x 64
  float* hS  = (float*)(smem + 65536);    // 256 x 64

  const int jjloc = wn * 16 + l16;        // 0..63 within block tile
#pragma unroll
  for (int i = 0; i < 8; ++i) {
    const int rbase = m0 + wm * 128 + i * 16 + quad * 4;
    float cv[4];
#pragma unroll
    for (int r = 0; r < 4; ++r)
      cv[r] = C[(size_t)(rbase + r) * OUT_F + jj];
#pragma unroll
    for (int r = 0; r < 4; ++r) {
      const float c = cv[r];
      const float inn = tanhf_(acc[i][2][r] + nb);
      const float fg  = sigmoidf_(fwc * c + acc[i][0][r] + fb);
      const float ig  = sigmoidf_(iwc * c + acc[i][1][r] + ib);
      const float cm  = fg * c + ig * inn;
      const float og  = sigmoidf_(owc * cm + acc[i][3][r] + ob);
      const int rloc = wm * 128 + i * 16 + quad * 4 + r;
      cmS[rloc * 64 + jjloc] = cm;
      hS [rloc * 64 + jjloc] = og * tanhf_(cm);
    }
  }
  __syncthreads();

  // cooperative coalesced store: 256 rows x 64 cols per tile; each row is a
  // contiguous 256B (two full HBM lines) — no write amplification.
  const int ub = blockIdx.x * 64;
#pragma unroll
  for (int q = 0; q < 8; ++q) {
    const int idx = q * 512 + tid;
    const int row = idx >> 4;            // 0..255
    const int c4 = idx & 15;             // float4 slot within row
    const size_t gbase = (size_t)(m0 + row) * OUT_F + ub + c4 * 4;
    *(float4*)(out + gbase) = *(const float4*)(cmS + row * 64 + c4 * 4);
    *(float4*)(out + HSIZE + gbase) = *(const float4*)(hS + row * 64 + c4 * 4);
  }
}

// ---------------------------------------------------------------------------
extern "C" void kernel_launch(void* const* d_in, const int* in_sizes, int n_in,
                              void* d_out, int out_size, void* d_ws, size_t ws_size,
                              hipStream_t stream) {
  const float* x       = (const float*)d_in[0];
  const float* C       = (const float*)d_in[1];
  const float* H       = (const float*)d_in[2];
  const float* fg_w_c  = (const float*)d_in[3];
  const float* fg_w_h  = (const float*)d_in[4];
  const float* fg_w_x  = (const float*)d_in[5];
  const float* fg_b    = (const float*)d_in[6];
  const float* ig_w_c  = (const float*)d_in[7];
  const float* ig_w_h  = (const float*)d_in[8];
  const float* ig_w_x  = (const float*)d_in[9];
  const float* ig_b    = (const float*)d_in[10];
  const float* in_w_h  = (const float*)d_in[11];
  const float* in_w_x  = (const float*)d_in[12];
  const float* in_b    = (const float*)d_in[13];
  const float* og_w_cn = (const float*)d_in[14];
  const float* og_w_h  = (const float*)d_in[15];
  const float* og_w_x  = (const float*)d_in[16];
  const float* og_b    = (const float*)d_in[17];
  const int*   nptr    = (const int*)d_in[18];

  char* ws = (char*)d_ws;
  _Float16* Apk = (_Float16*)ws;                // 8192*768*2 = 12,582,912 B
  _Float16* Wpk = (_Float16*)(ws + 12582912);   // 2048*768*2 =  3,145,728 B
  (void)ws_size; (void)in_sizes; (void)n_in; (void)out_size;

  pack_AW<<<(BATCH + NDIM) / PACK_ROWS, 192, 0, stream>>>(
      H, x, nptr,
      fg_w_h, fg_w_x, ig_w_h, ig_w_x,
      in_w_h, in_w_x, og_w_h, og_w_x,
      Apk, Wpk);
  dim3 grid(NDIM / BN, BATCH / BM);  // (8, 32) = 256 blocks = 1/CU
  gemm_lstm<<<grid, 512, 0, stream>>>(Apk, Wpk, C,
                                      fg_w_c, fg_b, ig_w_c, ig_b, in_b,
                                      og_w_cn, og_b, (float*)d_out);
}